// Round 1
// baseline (424.861 us; speedup 1.0000x reference)
//
#include <hip/hip_runtime.h>

// Problem: B=16384, DIM=64, F=8 coupling steps, H=8 hidden, D2=32.
// y = J^{-1} g with g = -2(x - x_star), J = Jacobian of the coupling flow.
// We apply J^{-1} analytically: per step J_step = J_T2 J_T1 with triangular
// block structure; inverse application needs only MLP JVPs (no matrices).
// Intermediate states recovered by inverting the flow from z = phi(x).

namespace {

constexpr int NB    = 16384;
constexpr int NSTEP = 8;

__device__ __forceinline__ float frcp(float x) { return __builtin_amdgcn_rcpf(x); }

__device__ __forceinline__ float ftanh(float x) {
  // tanh(x) = (e^{2x}-1)/(e^{2x}+1); clamp so e^{2x} stays finite.
  float xc = fminf(fmaxf(x, -15.f), 15.f);
  float e  = __expf(2.f * xc);
  return (e - 1.f) * frcp(e + 1.f);
}

// fcnn: out = w2 @ tanh(w1 @ tanh(w0 @ v + c0) + c1) + c2
// w0: [8][32] (LDS), w1: [8][8] (global, uniform), w2: [32][8] (LDS)
template <bool SAVE>
__device__ __forceinline__ void fcnn_eval(
    const float* __restrict__ w0, const float* __restrict__ c0,
    const float* __restrict__ w1, const float* __restrict__ c1,
    const float* __restrict__ w2, const float* __restrict__ c2,
    const float v[32], float out[32], float* h1s, float* h2s) {
  float h1[8], h2[8];
#pragma unroll
  for (int j = 0; j < 8; ++j) {
    float acc = c0[j];
#pragma unroll
    for (int k = 0; k < 32; ++k) acc = fmaf(w0[j * 32 + k], v[k], acc);
    h1[j] = ftanh(acc);
  }
#pragma unroll
  for (int j = 0; j < 8; ++j) {
    float acc = c1[j];
#pragma unroll
    for (int k = 0; k < 8; ++k) acc = fmaf(w1[j * 8 + k], h1[k], acc);
    h2[j] = ftanh(acc);
  }
#pragma unroll
  for (int j = 0; j < 32; ++j) {
    float acc = c2[j];
#pragma unroll
    for (int k = 0; k < 8; ++k) acc = fmaf(w2[j * 8 + k], h2[k], acc);
    out[j] = acc;
  }
  if constexpr (SAVE) {
#pragma unroll
    for (int j = 0; j < 8; ++j) {
      h1s[j] = h1[j];
      h2s[j] = h2[j];
    }
  }
}

// JVP of fcnn at a point with saved post-tanh activations h1, h2:
// r = w2 @ (diag(1-h2^2) @ (w1 @ (diag(1-h1^2) @ (w0 @ u))))
__device__ __forceinline__ void fcnn_jvp(
    const float* __restrict__ w0, const float* __restrict__ w1,
    const float* __restrict__ w2, const float h1[8], const float h2[8],
    const float u[32], float r[32]) {
  float g1[8], g2[8];
#pragma unroll
  for (int j = 0; j < 8; ++j) {
    float acc = 0.f;
#pragma unroll
    for (int k = 0; k < 32; ++k) acc = fmaf(w0[j * 32 + k], u[k], acc);
    g1[j] = (1.f - h1[j] * h1[j]) * acc;
  }
#pragma unroll
  for (int j = 0; j < 8; ++j) {
    float acc = 0.f;
#pragma unroll
    for (int k = 0; k < 8; ++k) acc = fmaf(w1[j * 8 + k], g1[k], acc);
    g2[j] = (1.f - h2[j] * h2[j]) * acc;
  }
#pragma unroll
  for (int j = 0; j < 32; ++j) {
    float acc = 0.f;
#pragma unroll
    for (int k = 0; k < 8; ++k) acc = fmaf(w2[j * 8 + k], g2[k], acc);
    r[j] = acc;
  }
}

}  // namespace

// Block = 64 threads (1 wave), grid = 256 blocks: one wave per CU.
// LDS: W0 (8*4*8*32 floats = 32 KiB) + W2 (8*4*32*8 floats = 32 KiB) = 64 KiB.
// W1/biases are read through wave-uniform addresses (scalar-load path).
__global__ __launch_bounds__(64, 1) void nf_policy_kernel(
    const float* __restrict__ x, const float* __restrict__ xs,
    const float* __restrict__ gW0, const float* __restrict__ gb0,
    const float* __restrict__ gW1, const float* __restrict__ gb1,
    const float* __restrict__ gW2, const float* __restrict__ gb2,
    float* __restrict__ out) {
  __shared__ float sW0[8192];  // [F*4][8][32]
  __shared__ float sW2[8192];  // [F*4][32][8]

  const int tid = threadIdx.x;
  {
    const float4* s0 = (const float4*)gW0;
    const float4* s2 = (const float4*)gW2;
    float4* d0 = (float4*)sW0;
    float4* d2 = (float4*)sW2;
    for (int i = tid; i < 2048; i += 64) {
      d0[i] = s0[i];
      d2[i] = s2[i];
    }
  }
  __syncthreads();

  const int b = blockIdx.x * 64 + tid;
  if (b >= NB) return;

  float lo[32], up[32], av[32], bv[32];
#pragma unroll
  for (int k = 0; k < 32; ++k) {
    float xl = x[(size_t)b * 64 + k];
    float xu = x[(size_t)b * 64 + 32 + k];
    float sl = xs[(size_t)b * 64 + k];
    float su = xs[(size_t)b * 64 + 32 + k];
    lo[k] = xl;
    up[k] = xu;
    av[k] = -2.f * (xl - sl);  // g, lower half
    bv[k] = -2.f * (xu - su);  // g, upper half
  }

  float t[32], s[32];

  // ---------------- forward: z = phi(x) ----------------
  for (int i = 0; i < NSTEP; ++i) {
    {
      const int m0 = i * 4 + 0, m1 = i * 4 + 1;
      fcnn_eval<false>(sW0 + m0 * 256, gb0 + m0 * 8, gW1 + m0 * 64, gb1 + m0 * 8,
                       sW2 + m0 * 256, gb2 + m0 * 32, lo, t, nullptr, nullptr);
      fcnn_eval<false>(sW0 + m1 * 256, gb0 + m1 * 8, gW1 + m1 * 64, gb1 + m1 * 8,
                       sW2 + m1 * 256, gb2 + m1 * 32, lo, s, nullptr, nullptr);
#pragma unroll
      for (int k = 0; k < 32; ++k) up[k] = t[k] + up[k] * __expf(s[k]);
    }
    {
      const int m2 = i * 4 + 2, m3 = i * 4 + 3;
      fcnn_eval<false>(sW0 + m2 * 256, gb0 + m2 * 8, gW1 + m2 * 64, gb1 + m2 * 8,
                       sW2 + m2 * 256, gb2 + m2 * 32, up, t, nullptr, nullptr);
      fcnn_eval<false>(sW0 + m3 * 256, gb0 + m3 * 8, gW1 + m3 * 64, gb1 + m3 * 8,
                       sW2 + m3 * 256, gb2 + m3 * 32, up, s, nullptr, nullptr);
#pragma unroll
      for (int k = 0; k < 32; ++k) lo[k] = t[k] + lo[k] * __expf(s[k]);
    }
  }

  // ---------------- backward: y = J^{-1} g, inverting the flow ----------
  // J^{-1} = J_0^{-1} ... J_7^{-1};  J_i^{-1} = J_T1^{-1} J_T2^{-1}.
  float es[32], u[32];
  float h1t[8], h2t[8], h1s[8], h2s[8];
  for (int i = NSTEP - 1; i >= 0; --i) {
    // ---- T2^{-1}: lo' -> lo, then a <- e^{-s2} (a - M2 b) ----
    {
      const int m2 = i * 4 + 2, m3 = i * 4 + 3;
      fcnn_eval<true>(sW0 + m2 * 256, gb0 + m2 * 8, gW1 + m2 * 64, gb1 + m2 * 8,
                      sW2 + m2 * 256, gb2 + m2 * 32, up, t, h1t, h2t);  // t2(up')
      fcnn_eval<true>(sW0 + m3 * 256, gb0 + m3 * 8, gW1 + m3 * 64, gb1 + m3 * 8,
                      sW2 + m3 * 256, gb2 + m3 * 32, up, s, h1s, h2s);  // s2(up')
#pragma unroll
      for (int k = 0; k < 32; ++k) es[k] = __expf(s[k]);
#pragma unroll
      for (int k = 0; k < 32; ++k) lo[k] = (lo[k] - t[k]) * frcp(es[k]);  // pre-step lo
      fcnn_jvp(sW0 + m2 * 256, gW1 + m2 * 64, sW2 + m2 * 256, h1t, h2t, bv, u);
#pragma unroll
      for (int k = 0; k < 32; ++k) av[k] -= u[k];
      fcnn_jvp(sW0 + m3 * 256, gW1 + m3 * 64, sW2 + m3 * 256, h1s, h2s, bv, u);
#pragma unroll
      for (int k = 0; k < 32; ++k)
        av[k] = (av[k] - lo[k] * es[k] * u[k]) * frcp(es[k]);
    }
    // ---- T1^{-1}: up' -> up, then b <- e^{-s1} (b - M1 a_new) ----
    {
      const int m0 = i * 4 + 0, m1 = i * 4 + 1;
      fcnn_eval<true>(sW0 + m0 * 256, gb0 + m0 * 8, gW1 + m0 * 64, gb1 + m0 * 8,
                      sW2 + m0 * 256, gb2 + m0 * 32, lo, t, h1t, h2t);  // t1(lo)
      fcnn_eval<true>(sW0 + m1 * 256, gb0 + m1 * 8, gW1 + m1 * 64, gb1 + m1 * 8,
                      sW2 + m1 * 256, gb2 + m1 * 32, lo, s, h1s, h2s);  // s1(lo)
#pragma unroll
      for (int k = 0; k < 32; ++k) es[k] = __expf(s[k]);
#pragma unroll
      for (int k = 0; k < 32; ++k) up[k] = (up[k] - t[k]) * frcp(es[k]);  // pre-step up
      fcnn_jvp(sW0 + m0 * 256, gW1 + m0 * 64, sW2 + m0 * 256, h1t, h2t, av, u);
#pragma unroll
      for (int k = 0; k < 32; ++k) bv[k] -= u[k];
      fcnn_jvp(sW0 + m1 * 256, gW1 + m1 * 64, sW2 + m1 * 256, h1s, h2s, av, u);
#pragma unroll
      for (int k = 0; k < 32; ++k)
        bv[k] = (bv[k] - up[k] * es[k] * u[k]) * frcp(es[k]);
    }
  }

#pragma unroll
  for (int k = 0; k < 32; ++k) {
    out[(size_t)b * 64 + k] = av[k];
    out[(size_t)b * 64 + 32 + k] = bv[k];
  }
}

extern "C" void kernel_launch(void* const* d_in, const int* in_sizes, int n_in,
                              void* d_out, int out_size, void* d_ws,
                              size_t ws_size, hipStream_t stream) {
  const float* x  = (const float*)d_in[0];
  const float* xs = (const float*)d_in[1];
  const float* W0 = (const float*)d_in[2];
  const float* b0 = (const float*)d_in[3];
  const float* W1 = (const float*)d_in[4];
  const float* b1 = (const float*)d_in[5];
  const float* W2 = (const float*)d_in[6];
  const float* b2 = (const float*)d_in[7];
  float* out = (float*)d_out;

  dim3 grid(NB / 64);
  dim3 block(64);
  nf_policy_kernel<<<grid, block, 0, stream>>>(x, xs, W0, b0, W1, b1, W2, b2,
                                               out);
}

// Round 2
// 179.817 us; speedup vs baseline: 2.3627x; 2.3627x over previous
//
#include <hip/hip_runtime.h>

// B=16384, DIM=64, 8 coupling steps, H=8, D2=32.
// y = J^{-1} g applied analytically via triangular-block inverses + MLP JVPs;
// intermediate flow states recovered by inverting the flow from z = phi(x).
//
// Parallelization: 4 lanes (one quad) per batch element. Each lane owns 8 of
// the 32 dims of every 32-vector. Quad reductions via DPP quad_perm adds
// (VALU-only). W0 and W2^T staged in LDS (broadcast reads, conflict-free);
// W1/b0/b1 read wave-uniform (scalar-load path); b2 staged in LDS.

namespace {

constexpr int NB    = 16384;
constexpr int NSTEP = 8;

__device__ __forceinline__ float frcp(float x) { return __builtin_amdgcn_rcpf(x); }

__device__ __forceinline__ float ftanh(float x) {
  float xc = fminf(fmaxf(x, -15.f), 15.f);
  float e  = __expf(2.f * xc);
  return (e - 1.f) * frcp(e + 1.f);
}

// quad_perm DPP add: CTRL 0xB1 = swap-xor1 {1,0,3,2}, 0x4E = swap-xor2 {2,3,0,1}
template <int CTRL>
__device__ __forceinline__ float dpp_add(float v) {
  int p = __builtin_amdgcn_update_dpp(0, __float_as_int(v), CTRL, 0xF, 0xF, true);
  return v + __int_as_float(p);
}
__device__ __forceinline__ float quad_sum(float v) {
  return dpp_add<0x4E>(dpp_add<0xB1>(v));
}

// Distributed fcnn: v8/out8 hold dims q*8..q*8+7. h1/h2 full (redundant/lane).
// w0: LDS [8][32]; c0,w1,c1: global wave-uniform; w2t: LDS [8][32] (k-major,
// i.e. w2t[k*32+d2] = W2[d2][k]); c2: LDS [32].
template <bool SAVE>
__device__ __forceinline__ void fcnn_q(
    const float* __restrict__ w0, const float* __restrict__ c0,
    const float* __restrict__ w1, const float* __restrict__ c1,
    const float* __restrict__ w2t, const float* __restrict__ c2,
    int q, const float v8[8], float out8[8], float* h1s, float* h2s) {
  float h1[8], h2[8];
#pragma unroll
  for (int j = 0; j < 8; ++j) {
    const float4* wq = (const float4*)(w0 + j * 32 + q * 8);
    float4 a = wq[0], bq = wq[1];
    float acc = a.x * v8[0];
    acc = fmaf(a.y, v8[1], acc);
    acc = fmaf(a.z, v8[2], acc);
    acc = fmaf(a.w, v8[3], acc);
    acc = fmaf(bq.x, v8[4], acc);
    acc = fmaf(bq.y, v8[5], acc);
    acc = fmaf(bq.z, v8[6], acc);
    acc = fmaf(bq.w, v8[7], acc);
    acc = quad_sum(acc);
    h1[j] = ftanh(acc + c0[j]);
  }
#pragma unroll
  for (int j = 0; j < 8; ++j) {
    float acc = c1[j];
#pragma unroll
    for (int k = 0; k < 8; ++k) acc = fmaf(w1[j * 8 + k], h1[k], acc);
    h2[j] = ftanh(acc);
  }
  const float4* cq = (const float4*)(c2 + q * 8);
  float4 ca = cq[0], cb = cq[1];
  float o0 = ca.x, o1 = ca.y, o2 = ca.z, o3 = ca.w;
  float o4 = cb.x, o5 = cb.y, o6 = cb.z, o7 = cb.w;
#pragma unroll
  for (int k = 0; k < 8; ++k) {
    const float4* wq = (const float4*)(w2t + k * 32 + q * 8);
    float4 a = wq[0], bq = wq[1];
    float hk = h2[k];
    o0 = fmaf(a.x, hk, o0);
    o1 = fmaf(a.y, hk, o1);
    o2 = fmaf(a.z, hk, o2);
    o3 = fmaf(a.w, hk, o3);
    o4 = fmaf(bq.x, hk, o4);
    o5 = fmaf(bq.y, hk, o5);
    o6 = fmaf(bq.z, hk, o6);
    o7 = fmaf(bq.w, hk, o7);
  }
  out8[0] = o0; out8[1] = o1; out8[2] = o2; out8[3] = o3;
  out8[4] = o4; out8[5] = o5; out8[6] = o6; out8[7] = o7;
  if constexpr (SAVE) {
#pragma unroll
    for (int j = 0; j < 8; ++j) { h1s[j] = h1[j]; h2s[j] = h2[j]; }
  }
}

// JVP through fcnn at saved activations h1,h2 (full per lane).
__device__ __forceinline__ void fcnn_jvp_q(
    const float* __restrict__ w0, const float* __restrict__ w1,
    const float* __restrict__ w2t, const float h1[8], const float h2[8],
    int q, const float u8[8], float r8[8]) {
  float g1[8], g2[8];
#pragma unroll
  for (int j = 0; j < 8; ++j) {
    const float4* wq = (const float4*)(w0 + j * 32 + q * 8);
    float4 a = wq[0], bq = wq[1];
    float acc = a.x * u8[0];
    acc = fmaf(a.y, u8[1], acc);
    acc = fmaf(a.z, u8[2], acc);
    acc = fmaf(a.w, u8[3], acc);
    acc = fmaf(bq.x, u8[4], acc);
    acc = fmaf(bq.y, u8[5], acc);
    acc = fmaf(bq.z, u8[6], acc);
    acc = fmaf(bq.w, u8[7], acc);
    acc = quad_sum(acc);
    g1[j] = (1.f - h1[j] * h1[j]) * acc;
  }
#pragma unroll
  for (int j = 0; j < 8; ++j) {
    float acc = 0.f;
#pragma unroll
    for (int k = 0; k < 8; ++k) acc = fmaf(w1[j * 8 + k], g1[k], acc);
    g2[j] = (1.f - h2[j] * h2[j]) * acc;
  }
  float o0 = 0.f, o1 = 0.f, o2 = 0.f, o3 = 0.f;
  float o4 = 0.f, o5 = 0.f, o6 = 0.f, o7 = 0.f;
#pragma unroll
  for (int k = 0; k < 8; ++k) {
    const float4* wq = (const float4*)(w2t + k * 32 + q * 8);
    float4 a = wq[0], bq = wq[1];
    float gk = g2[k];
    o0 = fmaf(a.x, gk, o0);
    o1 = fmaf(a.y, gk, o1);
    o2 = fmaf(a.z, gk, o2);
    o3 = fmaf(a.w, gk, o3);
    o4 = fmaf(bq.x, gk, o4);
    o5 = fmaf(bq.y, gk, o5);
    o6 = fmaf(bq.z, gk, o6);
    o7 = fmaf(bq.w, gk, o7);
  }
  r8[0] = o0; r8[1] = o1; r8[2] = o2; r8[3] = o3;
  r8[4] = o4; r8[5] = o5; r8[6] = o6; r8[7] = o7;
}

}  // namespace

// 256 threads/block = 64 elements/block, grid 256. LDS = 68 KiB -> 1 block/CU,
// 4 waves/CU (one per SIMD).
__global__ __launch_bounds__(256, 1) void nf_policy_kernel(
    const float* __restrict__ x, const float* __restrict__ xs,
    const float* __restrict__ gW0, const float* __restrict__ gb0,
    const float* __restrict__ gW1, const float* __restrict__ gb1,
    const float* __restrict__ gW2, const float* __restrict__ gb2,
    float* __restrict__ out) {
  __shared__ __align__(16) float sW0[8192];   // [32 mlp][8][32]
  __shared__ __align__(16) float sW2t[8192];  // [32 mlp][8 k][32 d2] (transposed)
  __shared__ __align__(16) float sB2[1024];   // [32 mlp][32]

  const int tid = threadIdx.x;
  {
    const float4* s0 = (const float4*)gW0;
    float4* d0 = (float4*)sW0;
#pragma unroll
    for (int i = tid; i < 2048; i += 256) d0[i] = s0[i];
    // W2 transpose: gW2 idx = m*256 + d2*8 + k  ->  sW2t[m*256 + k*32 + d2]
    for (int i = tid; i < 8192; i += 256) {
      int m = i >> 8, r = i & 255, d2 = r >> 3, k = r & 7;
      sW2t[m * 256 + k * 32 + d2] = gW2[i];
    }
    for (int i = tid; i < 1024; i += 256) sB2[i] = gb2[i];
  }
  __syncthreads();

  const int b = blockIdx.x * 64 + (tid >> 2);
  const int q = tid & 3;

  float lo8[8], up8[8], av8[8], bv8[8];
  {
    const float4* xl = (const float4*)(x + (size_t)b * 64 + q * 8);
    const float4* xu = (const float4*)(x + (size_t)b * 64 + 32 + q * 8);
    const float4* sl = (const float4*)(xs + (size_t)b * 64 + q * 8);
    const float4* su = (const float4*)(xs + (size_t)b * 64 + 32 + q * 8);
    float4 a, c;
    a = xl[0]; c = sl[0];
    lo8[0] = a.x; lo8[1] = a.y; lo8[2] = a.z; lo8[3] = a.w;
    av8[0] = -2.f * (a.x - c.x); av8[1] = -2.f * (a.y - c.y);
    av8[2] = -2.f * (a.z - c.z); av8[3] = -2.f * (a.w - c.w);
    a = xl[1]; c = sl[1];
    lo8[4] = a.x; lo8[5] = a.y; lo8[6] = a.z; lo8[7] = a.w;
    av8[4] = -2.f * (a.x - c.x); av8[5] = -2.f * (a.y - c.y);
    av8[6] = -2.f * (a.z - c.z); av8[7] = -2.f * (a.w - c.w);
    a = xu[0]; c = su[0];
    up8[0] = a.x; up8[1] = a.y; up8[2] = a.z; up8[3] = a.w;
    bv8[0] = -2.f * (a.x - c.x); bv8[1] = -2.f * (a.y - c.y);
    bv8[2] = -2.f * (a.z - c.z); bv8[3] = -2.f * (a.w - c.w);
    a = xu[1]; c = su[1];
    up8[4] = a.x; up8[5] = a.y; up8[6] = a.z; up8[7] = a.w;
    bv8[4] = -2.f * (a.x - c.x); bv8[5] = -2.f * (a.y - c.y);
    bv8[6] = -2.f * (a.z - c.z); bv8[7] = -2.f * (a.w - c.w);
  }

  float t8[8], s8[8];

  // ---------------- forward: z = phi(x) ----------------
  for (int i = 0; i < NSTEP; ++i) {
    {
      const int m0 = i * 4 + 0, m1 = i * 4 + 1;
      fcnn_q<false>(sW0 + m0 * 256, gb0 + m0 * 8, gW1 + m0 * 64, gb1 + m0 * 8,
                    sW2t + m0 * 256, sB2 + m0 * 32, q, lo8, t8, nullptr, nullptr);
      fcnn_q<false>(sW0 + m1 * 256, gb0 + m1 * 8, gW1 + m1 * 64, gb1 + m1 * 8,
                    sW2t + m1 * 256, sB2 + m1 * 32, q, lo8, s8, nullptr, nullptr);
#pragma unroll
      for (int k = 0; k < 8; ++k) up8[k] = fmaf(up8[k], __expf(s8[k]), t8[k]);
    }
    {
      const int m2 = i * 4 + 2, m3 = i * 4 + 3;
      fcnn_q<false>(sW0 + m2 * 256, gb0 + m2 * 8, gW1 + m2 * 64, gb1 + m2 * 8,
                    sW2t + m2 * 256, sB2 + m2 * 32, q, up8, t8, nullptr, nullptr);
      fcnn_q<false>(sW0 + m3 * 256, gb0 + m3 * 8, gW1 + m3 * 64, gb1 + m3 * 8,
                    sW2t + m3 * 256, sB2 + m3 * 32, q, up8, s8, nullptr, nullptr);
#pragma unroll
      for (int k = 0; k < 8; ++k) lo8[k] = fmaf(lo8[k], __expf(s8[k]), t8[k]);
    }
  }

  // ------------- backward: y = J^{-1} g, inverting the flow -------------
  float es8[8], u8[8];
  float h1t[8], h2t[8], h1s[8], h2s[8];
  for (int i = NSTEP - 1; i >= 0; --i) {
    {  // T2^{-1}
      const int m2 = i * 4 + 2, m3 = i * 4 + 3;
      fcnn_q<true>(sW0 + m2 * 256, gb0 + m2 * 8, gW1 + m2 * 64, gb1 + m2 * 8,
                   sW2t + m2 * 256, sB2 + m2 * 32, q, up8, t8, h1t, h2t);
      fcnn_q<true>(sW0 + m3 * 256, gb0 + m3 * 8, gW1 + m3 * 64, gb1 + m3 * 8,
                   sW2t + m3 * 256, sB2 + m3 * 32, q, up8, s8, h1s, h2s);
#pragma unroll
      for (int k = 0; k < 8; ++k) es8[k] = __expf(s8[k]);
#pragma unroll
      for (int k = 0; k < 8; ++k) lo8[k] = (lo8[k] - t8[k]) * frcp(es8[k]);
      fcnn_jvp_q(sW0 + m2 * 256, gW1 + m2 * 64, sW2t + m2 * 256, h1t, h2t, q,
                 bv8, u8);
#pragma unroll
      for (int k = 0; k < 8; ++k) av8[k] -= u8[k];
      fcnn_jvp_q(sW0 + m3 * 256, gW1 + m3 * 64, sW2t + m3 * 256, h1s, h2s, q,
                 bv8, u8);
#pragma unroll
      for (int k = 0; k < 8; ++k)
        av8[k] = (av8[k] - lo8[k] * es8[k] * u8[k]) * frcp(es8[k]);
    }
    {  // T1^{-1}
      const int m0 = i * 4 + 0, m1 = i * 4 + 1;
      fcnn_q<true>(sW0 + m0 * 256, gb0 + m0 * 8, gW1 + m0 * 64, gb1 + m0 * 8,
                   sW2t + m0 * 256, sB2 + m0 * 32, q, lo8, t8, h1t, h2t);
      fcnn_q<true>(sW0 + m1 * 256, gb0 + m1 * 8, gW1 + m1 * 64, gb1 + m1 * 8,
                   sW2t + m1 * 256, sB2 + m1 * 32, q, lo8, s8, h1s, h2s);
#pragma unroll
      for (int k = 0; k < 8; ++k) es8[k] = __expf(s8[k]);
#pragma unroll
      for (int k = 0; k < 8; ++k) up8[k] = (up8[k] - t8[k]) * frcp(es8[k]);
      fcnn_jvp_q(sW0 + m0 * 256, gW1 + m0 * 64, sW2t + m0 * 256, h1t, h2t, q,
                 av8, u8);
#pragma unroll
      for (int k = 0; k < 8; ++k) bv8[k] -= u8[k];
      fcnn_jvp_q(sW0 + m1 * 256, gW1 + m1 * 64, sW2t + m1 * 256, h1s, h2s, q,
                 av8, u8);
#pragma unroll
      for (int k = 0; k < 8; ++k)
        bv8[k] = (bv8[k] - up8[k] * es8[k] * u8[k]) * frcp(es8[k]);
    }
  }

  {
    float4* ol = (float4*)(out + (size_t)b * 64 + q * 8);
    float4* ou = (float4*)(out + (size_t)b * 64 + 32 + q * 8);
    float4 v;
    v.x = av8[0]; v.y = av8[1]; v.z = av8[2]; v.w = av8[3]; ol[0] = v;
    v.x = av8[4]; v.y = av8[5]; v.z = av8[6]; v.w = av8[7]; ol[1] = v;
    v.x = bv8[0]; v.y = bv8[1]; v.z = bv8[2]; v.w = bv8[3]; ou[0] = v;
    v.x = bv8[4]; v.y = bv8[5]; v.z = bv8[6]; v.w = bv8[7]; ou[1] = v;
  }
}

extern "C" void kernel_launch(void* const* d_in, const int* in_sizes, int n_in,
                              void* d_out, int out_size, void* d_ws,
                              size_t ws_size, hipStream_t stream) {
  const float* x  = (const float*)d_in[0];
  const float* xs = (const float*)d_in[1];
  const float* W0 = (const float*)d_in[2];
  const float* b0 = (const float*)d_in[3];
  const float* W1 = (const float*)d_in[4];
  const float* b1 = (const float*)d_in[5];
  const float* W2 = (const float*)d_in[6];
  const float* b2 = (const float*)d_in[7];
  float* out = (float*)d_out;

  dim3 grid(NB / 64);   // 256 blocks, 64 elements each
  dim3 block(256);
  nf_policy_kernel<<<grid, block, 0, stream>>>(x, xs, W0, b0, W1, b1, W2, b2,
                                               out);
}

// Round 3
// 153.331 us; speedup vs baseline: 2.7709x; 1.1727x over previous
//
#include <hip/hip_runtime.h>

// B=16384, DIM=64, 8 coupling steps, H=8, D2=32.
// y = J^{-1} g applied analytically (triangular coupling blocks -> MLP JVPs);
// intermediate states recovered by inverting the flow from z = phi(x).
//
// Parallelization: 8 lanes (2 quads) per batch element.
//  - lane q = tid&3 owns dims 8q..8q+7 of every 32-vector (both quads hold
//    the full state redundantly).
//  - quad parity hb = (tid>>2)&1 selects the net: hb=0 -> t-net, hb=1 -> s-net.
//    Each half-step each quad evaluates ONE MLP; t/s results are exchanged
//    via ds_swizzle xor-4 (lane l <-> l^4, stays inside the 8-lane element).
//  - layer-1 partial dots reduced across the quad with DPP quad_perm adds.
//  - backward fuses eval+JVP in one pass sharing all weight loads.
// All weights/biases staged in LDS (78 KiB -> 2 blocks/CU, 8 waves/CU).

namespace {

constexpr int NB    = 16384;
constexpr int NSTEP = 8;

__device__ __forceinline__ float frcp(float x) { return __builtin_amdgcn_rcpf(x); }

__device__ __forceinline__ float ftanh(float x) {
  float xc = fminf(fmaxf(x, -15.f), 15.f);
  float e  = __expf(2.f * xc);
  return (e - 1.f) * frcp(e + 1.f);
}

// quad_perm DPP add: 0xB1 = xor1 {1,0,3,2}, 0x4E = xor2 {2,3,0,1}
template <int CTRL>
__device__ __forceinline__ float dpp_add(float v) {
  int p = __builtin_amdgcn_update_dpp(0, __float_as_int(v), CTRL, 0xF, 0xF, true);
  return v + __int_as_float(p);
}
__device__ __forceinline__ float quad_sum(float v) {
  return dpp_add<0x4E>(dpp_add<0xB1>(v));
}

// lane l <-> l^4 (BitMode: xor=4, and=0x1F, or=0 -> offset 0x101F)
__device__ __forceinline__ float swz_x4(float v) {
  return __int_as_float(__builtin_amdgcn_ds_swizzle(__float_as_int(v), 0x101F));
}

// Fused fcnn eval (+ optional JVP sharing the weight loads).
// w0: LDS [8][32]; c0,c1: LDS [8]; w1: LDS [8][8]; w2t: LDS [8][32] (k-major);
// c2: LDS [32]. v8/u8/out8/jout8 hold dims q*8..q*8+7.
template <bool JVP>
__device__ __forceinline__ void fcnn8(
    const float* __restrict__ w0, const float* __restrict__ c0,
    const float* __restrict__ w1, const float* __restrict__ c1,
    const float* __restrict__ w2t, const float* __restrict__ c2,
    int q, const float v8[8], const float* __restrict__ u8, float out8[8],
    float* __restrict__ jout8) {
  float cb0[8], cb1[8];
  {
    const float4* p = (const float4*)c0;
    float4 a = p[0], b = p[1];
    cb0[0] = a.x; cb0[1] = a.y; cb0[2] = a.z; cb0[3] = a.w;
    cb0[4] = b.x; cb0[5] = b.y; cb0[6] = b.z; cb0[7] = b.w;
  }
  {
    const float4* p = (const float4*)c1;
    float4 a = p[0], b = p[1];
    cb1[0] = a.x; cb1[1] = a.y; cb1[2] = a.z; cb1[3] = a.w;
    cb1[4] = b.x; cb1[5] = b.y; cb1[6] = b.z; cb1[7] = b.w;
  }
  float h1[8], g1[8];
#pragma unroll
  for (int j = 0; j < 8; ++j) {
    const float4* wq = (const float4*)(w0 + j * 32 + q * 8);
    float4 a = wq[0], b = wq[1];
    float av = a.x * v8[0];
    av = fmaf(a.y, v8[1], av);
    av = fmaf(a.z, v8[2], av);
    av = fmaf(a.w, v8[3], av);
    av = fmaf(b.x, v8[4], av);
    av = fmaf(b.y, v8[5], av);
    av = fmaf(b.z, v8[6], av);
    av = fmaf(b.w, v8[7], av);
    av = quad_sum(av);
    h1[j] = ftanh(av + cb0[j]);
    if constexpr (JVP) {
      float au = a.x * u8[0];
      au = fmaf(a.y, u8[1], au);
      au = fmaf(a.z, u8[2], au);
      au = fmaf(a.w, u8[3], au);
      au = fmaf(b.x, u8[4], au);
      au = fmaf(b.y, u8[5], au);
      au = fmaf(b.z, u8[6], au);
      au = fmaf(b.w, u8[7], au);
      au = quad_sum(au);
      g1[j] = (1.f - h1[j] * h1[j]) * au;
    }
  }
  float h2[8], g2[8];
#pragma unroll
  for (int j = 0; j < 8; ++j) {
    const float4* wr = (const float4*)(w1 + j * 8);
    float4 a = wr[0], b = wr[1];
    float av = cb1[j];
    av = fmaf(a.x, h1[0], av);
    av = fmaf(a.y, h1[1], av);
    av = fmaf(a.z, h1[2], av);
    av = fmaf(a.w, h1[3], av);
    av = fmaf(b.x, h1[4], av);
    av = fmaf(b.y, h1[5], av);
    av = fmaf(b.z, h1[6], av);
    av = fmaf(b.w, h1[7], av);
    h2[j] = ftanh(av);
    if constexpr (JVP) {
      float au = a.x * g1[0];
      au = fmaf(a.y, g1[1], au);
      au = fmaf(a.z, g1[2], au);
      au = fmaf(a.w, g1[3], au);
      au = fmaf(b.x, g1[4], au);
      au = fmaf(b.y, g1[5], au);
      au = fmaf(b.z, g1[6], au);
      au = fmaf(b.w, g1[7], au);
      g2[j] = (1.f - h2[j] * h2[j]) * au;
    }
  }
  float o[8], jo[8];
  {
    const float4* p = (const float4*)(c2 + q * 8);
    float4 a = p[0], b = p[1];
    o[0] = a.x; o[1] = a.y; o[2] = a.z; o[3] = a.w;
    o[4] = b.x; o[5] = b.y; o[6] = b.z; o[7] = b.w;
  }
  if constexpr (JVP) {
#pragma unroll
    for (int k = 0; k < 8; ++k) jo[k] = 0.f;
  }
#pragma unroll
  for (int k = 0; k < 8; ++k) {
    const float4* wq = (const float4*)(w2t + k * 32 + q * 8);
    float4 a = wq[0], b = wq[1];
    float hk = h2[k];
    o[0] = fmaf(a.x, hk, o[0]);
    o[1] = fmaf(a.y, hk, o[1]);
    o[2] = fmaf(a.z, hk, o[2]);
    o[3] = fmaf(a.w, hk, o[3]);
    o[4] = fmaf(b.x, hk, o[4]);
    o[5] = fmaf(b.y, hk, o[5]);
    o[6] = fmaf(b.z, hk, o[6]);
    o[7] = fmaf(b.w, hk, o[7]);
    if constexpr (JVP) {
      float gk = g2[k];
      jo[0] = fmaf(a.x, gk, jo[0]);
      jo[1] = fmaf(a.y, gk, jo[1]);
      jo[2] = fmaf(a.z, gk, jo[2]);
      jo[3] = fmaf(a.w, gk, jo[3]);
      jo[4] = fmaf(b.x, gk, jo[4]);
      jo[5] = fmaf(b.y, gk, jo[5]);
      jo[6] = fmaf(b.z, gk, jo[6]);
      jo[7] = fmaf(b.w, gk, jo[7]);
    }
  }
#pragma unroll
  for (int k = 0; k < 8; ++k) out8[k] = o[k];
  if constexpr (JVP) {
#pragma unroll
    for (int k = 0; k < 8; ++k) jout8[k] = jo[k];
  }
}

}  // namespace

// 256 threads/block = 32 elements/block, grid 512 -> 2 blocks/CU (78 KiB LDS),
// 8 waves/CU = 2 per SIMD.
__global__ __launch_bounds__(256, 2) void nf_policy_kernel(
    const float* __restrict__ x, const float* __restrict__ xs,
    const float* __restrict__ gW0, const float* __restrict__ gb0,
    const float* __restrict__ gW1, const float* __restrict__ gb1,
    const float* __restrict__ gW2, const float* __restrict__ gb2,
    float* __restrict__ out) {
  __shared__ __align__(16) float sW0[8192];   // [32 mlp][8][32]
  __shared__ __align__(16) float sW2t[8192];  // [32 mlp][8 k][32 d2]
  __shared__ __align__(16) float sW1[2048];   // [32 mlp][8][8]
  __shared__ __align__(16) float sB0[256];    // [32 mlp][8]
  __shared__ __align__(16) float sB1[256];    // [32 mlp][8]
  __shared__ __align__(16) float sB2[1024];   // [32 mlp][32]

  const int tid = threadIdx.x;
  {
    const float4* s0 = (const float4*)gW0;
    float4* d0 = (float4*)sW0;
#pragma unroll
    for (int i = tid; i < 2048; i += 256) d0[i] = s0[i];
    const float4* s1 = (const float4*)gW1;
    float4* d1 = (float4*)sW1;
#pragma unroll
    for (int i = tid; i < 512; i += 256) d1[i] = s1[i];
    if (tid < 64) {
      ((float4*)sB0)[tid] = ((const float4*)gb0)[tid];
      ((float4*)sB1)[tid] = ((const float4*)gb1)[tid];
    }
#pragma unroll
    for (int i = tid; i < 256; i += 256) ((float4*)sB2)[i] = ((const float4*)gb2)[i];
    // W2 transpose: gW2 idx = m*256 + d2*8 + k  ->  sW2t[m*256 + k*32 + d2]
    for (int i = tid; i < 8192; i += 256) {
      int m = i >> 8, r = i & 255, d2 = r >> 3, k = r & 7;
      sW2t[m * 256 + k * 32 + d2] = gW2[i];
    }
  }
  __syncthreads();

  const int e  = blockIdx.x * 32 + (tid >> 3);
  const int q  = tid & 3;
  const bool hb = (tid >> 2) & 1;  // 0: t-net, 1: s-net

  float lo8[8], up8[8], av8[8], bv8[8];
  {
    const float4* xl = (const float4*)(x + (size_t)e * 64 + q * 8);
    const float4* xu = (const float4*)(x + (size_t)e * 64 + 32 + q * 8);
    const float4* sl = (const float4*)(xs + (size_t)e * 64 + q * 8);
    const float4* su = (const float4*)(xs + (size_t)e * 64 + 32 + q * 8);
    float4 a, c;
    a = xl[0]; c = sl[0];
    lo8[0] = a.x; lo8[1] = a.y; lo8[2] = a.z; lo8[3] = a.w;
    av8[0] = -2.f * (a.x - c.x); av8[1] = -2.f * (a.y - c.y);
    av8[2] = -2.f * (a.z - c.z); av8[3] = -2.f * (a.w - c.w);
    a = xl[1]; c = sl[1];
    lo8[4] = a.x; lo8[5] = a.y; lo8[6] = a.z; lo8[7] = a.w;
    av8[4] = -2.f * (a.x - c.x); av8[5] = -2.f * (a.y - c.y);
    av8[6] = -2.f * (a.z - c.z); av8[7] = -2.f * (a.w - c.w);
    a = xu[0]; c = su[0];
    up8[0] = a.x; up8[1] = a.y; up8[2] = a.z; up8[3] = a.w;
    bv8[0] = -2.f * (a.x - c.x); bv8[1] = -2.f * (a.y - c.y);
    bv8[2] = -2.f * (a.z - c.z); bv8[3] = -2.f * (a.w - c.w);
    a = xu[1]; c = su[1];
    up8[4] = a.x; up8[5] = a.y; up8[6] = a.z; up8[7] = a.w;
    bv8[4] = -2.f * (a.x - c.x); bv8[5] = -2.f * (a.y - c.y);
    bv8[6] = -2.f * (a.z - c.z); bv8[7] = -2.f * (a.w - c.w);
  }

  float r8[8], ru8[8], t8[8], s8[8], ut8[8], us8[8], es8[8];

  // ---------------- forward: z = phi(x) ----------------
  for (int i = 0; i < NSTEP; ++i) {
    {
      const int m = i * 4 + (int)hb;  // t1 (hb=0) / s1 (hb=1)
      fcnn8<false>(sW0 + m * 256, sB0 + m * 8, sW1 + m * 64, sB1 + m * 8,
                   sW2t + m * 256, sB2 + m * 32, q, lo8, nullptr, r8, nullptr);
#pragma unroll
      for (int k = 0; k < 8; ++k) {
        float o = swz_x4(r8[k]);
        t8[k] = hb ? o : r8[k];
        s8[k] = hb ? r8[k] : o;
      }
#pragma unroll
      for (int k = 0; k < 8; ++k) up8[k] = fmaf(up8[k], __expf(s8[k]), t8[k]);
    }
    {
      const int m = i * 4 + 2 + (int)hb;  // t2 / s2
      fcnn8<false>(sW0 + m * 256, sB0 + m * 8, sW1 + m * 64, sB1 + m * 8,
                   sW2t + m * 256, sB2 + m * 32, q, up8, nullptr, r8, nullptr);
#pragma unroll
      for (int k = 0; k < 8; ++k) {
        float o = swz_x4(r8[k]);
        t8[k] = hb ? o : r8[k];
        s8[k] = hb ? r8[k] : o;
      }
#pragma unroll
      for (int k = 0; k < 8; ++k) lo8[k] = fmaf(lo8[k], __expf(s8[k]), t8[k]);
    }
  }

  // ------------- backward: y = J^{-1} g, inverting the flow -------------
  for (int i = NSTEP - 1; i >= 0; --i) {
    {  // T2^{-1}: eval t2/s2 at up', jvp at bv
      const int m = i * 4 + 2 + (int)hb;
      fcnn8<true>(sW0 + m * 256, sB0 + m * 8, sW1 + m * 64, sB1 + m * 8,
                  sW2t + m * 256, sB2 + m * 32, q, up8, bv8, r8, ru8);
#pragma unroll
      for (int k = 0; k < 8; ++k) {
        float o = swz_x4(r8[k]);
        t8[k] = hb ? o : r8[k];
        s8[k] = hb ? r8[k] : o;
        float ou = swz_x4(ru8[k]);
        ut8[k] = hb ? ou : ru8[k];
        us8[k] = hb ? ru8[k] : ou;
      }
#pragma unroll
      for (int k = 0; k < 8; ++k) es8[k] = __expf(s8[k]);
#pragma unroll
      for (int k = 0; k < 8; ++k) lo8[k] = (lo8[k] - t8[k]) * frcp(es8[k]);
#pragma unroll
      for (int k = 0; k < 8; ++k)
        av8[k] = (av8[k] - ut8[k] - lo8[k] * es8[k] * us8[k]) * frcp(es8[k]);
    }
    {  // T1^{-1}: eval t1/s1 at lo (pre-step), jvp at av (updated)
      const int m = i * 4 + (int)hb;
      fcnn8<true>(sW0 + m * 256, sB0 + m * 8, sW1 + m * 64, sB1 + m * 8,
                  sW2t + m * 256, sB2 + m * 32, q, lo8, av8, r8, ru8);
#pragma unroll
      for (int k = 0; k < 8; ++k) {
        float o = swz_x4(r8[k]);
        t8[k] = hb ? o : r8[k];
        s8[k] = hb ? r8[k] : o;
        float ou = swz_x4(ru8[k]);
        ut8[k] = hb ? ou : ru8[k];
        us8[k] = hb ? ru8[k] : ou;
      }
#pragma unroll
      for (int k = 0; k < 8; ++k) es8[k] = __expf(s8[k]);
#pragma unroll
      for (int k = 0; k < 8; ++k) up8[k] = (up8[k] - t8[k]) * frcp(es8[k]);
#pragma unroll
      for (int k = 0; k < 8; ++k)
        bv8[k] = (bv8[k] - ut8[k] - up8[k] * es8[k] * us8[k]) * frcp(es8[k]);
    }
  }

  if (!hb) {
    float4* ol = (float4*)(out + (size_t)e * 64 + q * 8);
    float4* ou = (float4*)(out + (size_t)e * 64 + 32 + q * 8);
    float4 v;
    v.x = av8[0]; v.y = av8[1]; v.z = av8[2]; v.w = av8[3]; ol[0] = v;
    v.x = av8[4]; v.y = av8[5]; v.z = av8[6]; v.w = av8[7]; ol[1] = v;
    v.x = bv8[0]; v.y = bv8[1]; v.z = bv8[2]; v.w = bv8[3]; ou[0] = v;
    v.x = bv8[4]; v.y = bv8[5]; v.z = bv8[6]; v.w = bv8[7]; ou[1] = v;
  }
}

extern "C" void kernel_launch(void* const* d_in, const int* in_sizes, int n_in,
                              void* d_out, int out_size, void* d_ws,
                              size_t ws_size, hipStream_t stream) {
  const float* x  = (const float*)d_in[0];
  const float* xs = (const float*)d_in[1];
  const float* W0 = (const float*)d_in[2];
  const float* b0 = (const float*)d_in[3];
  const float* W1 = (const float*)d_in[4];
  const float* b1 = (const float*)d_in[5];
  const float* W2 = (const float*)d_in[6];
  const float* b2 = (const float*)d_in[7];
  float* out = (float*)d_out;

  dim3 grid(NB * 8 / 256);  // 512 blocks, 32 elements each
  dim3 block(256);
  nf_policy_kernel<<<grid, block, 0, stream>>>(x, xs, W0, b0, W1, b1, W2, b2,
                                               out);
}

// Round 5
// 124.111 us; speedup vs baseline: 3.4232x; 1.2354x over previous
//
#include <hip/hip_runtime.h>

// B=16384, DIM=64, 8 coupling steps, H=8, D2=32.
// y = J^{-1} g applied analytically (triangular coupling blocks -> MLP JVPs);
// intermediate states recovered by inverting the flow from z = phi(x).
//
// Mapping: 8 lanes / element. q = tid&3 owns dims {q*8..q*8+7} of each
// 32-vector; hb = (tid>>2)&1 selects t-net / s-net (results exchanged via
// ds_swizzle xor-4). Within a quad each lane computes FULL rows {q, q+4} of
// every MLP layer (zero FMA redundancy): layer-1 inputs gathered by 3 DPP
// quad-rotations of the packed input; h1/h2/g1/g2 pairs shared by 4 DPP
// quad-splats. All weights stored as packed f16x2 in LDS (bank-conflict-free
// pair layouts) and consumed with v_dot2_f32_f16 (fp32 accumulate).

namespace {

typedef _Float16 f16;
typedef f16 f16x2 __attribute__((ext_vector_type(2)));

constexpr int NB    = 16384;
constexpr int NSTEP = 8;

__device__ __forceinline__ float frcp(float x) { return __builtin_amdgcn_rcpf(x); }

__device__ __forceinline__ float ftanh(float x) {
  float e = __expf(2.f * x);
  return 1.f - 2.f * frcp(e + 1.f);
}

__device__ __forceinline__ float fdot2(f16x2 a, f16x2 b, float c) {
  return __builtin_amdgcn_fdot2(a, b, c, false);
}
__device__ __forceinline__ f16x2 pk(float a, float b) {
  auto r = __builtin_amdgcn_cvt_pkrtz(a, b);  // __fp16x2 on this toolchain
  return __builtin_bit_cast(f16x2, r);
}
template <int C>
__device__ __forceinline__ f16x2 dpp_h2(f16x2 v) {
  int r = __builtin_amdgcn_update_dpp(0, __builtin_bit_cast(int, v), C, 0xF, 0xF, true);
  return __builtin_bit_cast(f16x2, r);
}
// lane l <-> l^4 exchange (t/s across the two quads of an element)
__device__ __forceinline__ float swz_x4(float v) {
  return __int_as_float(__builtin_amdgcn_ds_swizzle(__float_as_int(v), 0x101F));
}
__device__ __forceinline__ void ld4h(const f16x2* p, f16x2& a, f16x2& b,
                                     f16x2& c, f16x2& d) {
  float4 w = *(const float4*)p;  // one ds_read_b128
  a = __builtin_bit_cast(f16x2, w.x);
  b = __builtin_bit_cast(f16x2, w.y);
  c = __builtin_bit_cast(f16x2, w.z);
  d = __builtin_bit_cast(f16x2, w.w);
}

// Apply one MLP (net m) and optionally its JVP, rows {q,q+4} per lane.
// hW0: [m][j(8)][16 pairs k]; hW1: [m][j(8)][4 pairs (p,p+4)];
// hW2: [m][r(8)][q(4)][4 pairs (p,p+4)] for out dim d=q*8+r;
// biases fp32.
template <bool JVP>
__device__ __forceinline__ void net_apply(
    const f16x2* __restrict__ hW0, const f16x2* __restrict__ hW1,
    const f16x2* __restrict__ hW2, const float* __restrict__ sB0,
    const float* __restrict__ sB1, const float* __restrict__ sB2,
    int m, int q, const float v8[8], const float* __restrict__ u8,
    float out8[8], float* __restrict__ jout8) {
  // pack own chunk, rotate to gather the full 32-dim vector
  f16x2 V[4][4], U[4][4];
#pragma unroll
  for (int p = 0; p < 4; ++p) V[0][p] = pk(v8[2 * p], v8[2 * p + 1]);
#pragma unroll
  for (int p = 0; p < 4; ++p) {
    V[1][p] = dpp_h2<0x39>(V[0][p]);  // chunk (q+1)&3
    V[2][p] = dpp_h2<0x4E>(V[0][p]);  // chunk (q+2)&3
    V[3][p] = dpp_h2<0x93>(V[0][p]);  // chunk (q+3)&3
  }
  if constexpr (JVP) {
#pragma unroll
    for (int p = 0; p < 4; ++p) U[0][p] = pk(u8[2 * p], u8[2 * p + 1]);
#pragma unroll
    for (int p = 0; p < 4; ++p) {
      U[1][p] = dpp_h2<0x39>(U[0][p]);
      U[2][p] = dpp_h2<0x4E>(U[0][p]);
      U[3][p] = dpp_h2<0x93>(U[0][p]);
    }
  }

  // ---- layer 1: full dots for rows q and q+4 ----
  const f16x2* W0m = hW0 + m * 128;
  float sva = 0.f, svb = 0.f, sua = 0.f, sub = 0.f;
#pragma unroll
  for (int r = 0; r < 4; ++r) {
    const int c = (q + r) & 3;
    f16x2 a0, a1, a2, a3, b0, b1, b2, b3;
    ld4h(W0m + q * 16 + c * 4, a0, a1, a2, a3);
    ld4h(W0m + (q + 4) * 16 + c * 4, b0, b1, b2, b3);
    sva = fdot2(a0, V[r][0], sva); sva = fdot2(a1, V[r][1], sva);
    sva = fdot2(a2, V[r][2], sva); sva = fdot2(a3, V[r][3], sva);
    svb = fdot2(b0, V[r][0], svb); svb = fdot2(b1, V[r][1], svb);
    svb = fdot2(b2, V[r][2], svb); svb = fdot2(b3, V[r][3], svb);
    if constexpr (JVP) {
      sua = fdot2(a0, U[r][0], sua); sua = fdot2(a1, U[r][1], sua);
      sua = fdot2(a2, U[r][2], sua); sua = fdot2(a3, U[r][3], sua);
      sub = fdot2(b0, U[r][0], sub); sub = fdot2(b1, U[r][1], sub);
      sub = fdot2(b2, U[r][2], sub); sub = fdot2(b3, U[r][3], sub);
    }
  }
  const float h1a = ftanh(sva + sB0[m * 8 + q]);
  const float h1b = ftanh(svb + sB0[m * 8 + q + 4]);
  const f16x2 h1p = pk(h1a, h1b);  // pair (h1[q], h1[q+4])
  f16x2 H1[4] = {dpp_h2<0x00>(h1p), dpp_h2<0x55>(h1p), dpp_h2<0xAA>(h1p),
                 dpp_h2<0xFF>(h1p)};
  f16x2 G1[4];
  if constexpr (JVP) {
    const float g1a = (1.f - h1a * h1a) * sua;
    const float g1b = (1.f - h1b * h1b) * sub;
    const f16x2 g1p = pk(g1a, g1b);
    G1[0] = dpp_h2<0x00>(g1p); G1[1] = dpp_h2<0x55>(g1p);
    G1[2] = dpp_h2<0xAA>(g1p); G1[3] = dpp_h2<0xFF>(g1p);
  }

  // ---- layer 2: rows q and q+4 ----
  f16x2 wa0, wa1, wa2, wa3, wb0, wb1, wb2, wb3;
  ld4h(hW1 + m * 32 + q * 4, wa0, wa1, wa2, wa3);
  ld4h(hW1 + m * 32 + q * 4 + 16, wb0, wb1, wb2, wb3);
  float t2a = sB1[m * 8 + q], t2b = sB1[m * 8 + q + 4];
  t2a = fdot2(wa0, H1[0], t2a); t2a = fdot2(wa1, H1[1], t2a);
  t2a = fdot2(wa2, H1[2], t2a); t2a = fdot2(wa3, H1[3], t2a);
  t2b = fdot2(wb0, H1[0], t2b); t2b = fdot2(wb1, H1[1], t2b);
  t2b = fdot2(wb2, H1[2], t2b); t2b = fdot2(wb3, H1[3], t2b);
  const float h2a = ftanh(t2a);
  const float h2b = ftanh(t2b);
  const f16x2 h2p = pk(h2a, h2b);
  f16x2 H2[4] = {dpp_h2<0x00>(h2p), dpp_h2<0x55>(h2p), dpp_h2<0xAA>(h2p),
                 dpp_h2<0xFF>(h2p)};
  f16x2 G2[4];
  if constexpr (JVP) {
    float ga = 0.f, gb = 0.f;
    ga = fdot2(wa0, G1[0], ga); ga = fdot2(wa1, G1[1], ga);
    ga = fdot2(wa2, G1[2], ga); ga = fdot2(wa3, G1[3], ga);
    gb = fdot2(wb0, G1[0], gb); gb = fdot2(wb1, G1[1], gb);
    gb = fdot2(wb2, G1[2], gb); gb = fdot2(wb3, G1[3], gb);
    const float g2a = (1.f - h2a * h2a) * ga;
    const float g2b = (1.f - h2b * h2b) * gb;
    const f16x2 g2p = pk(g2a, g2b);
    G2[0] = dpp_h2<0x00>(g2p); G2[1] = dpp_h2<0x55>(g2p);
    G2[2] = dpp_h2<0xAA>(g2p); G2[3] = dpp_h2<0xFF>(g2p);
  }

  // ---- layer 3: out dims d = q*8 + r ----
  const f16x2* W2m = hW2 + m * 128 + q * 4;
  const float4* b2v = (const float4*)(sB2 + m * 32 + q * 8);
  const float4 bl = b2v[0], bh = b2v[1];
  const float bb[8] = {bl.x, bl.y, bl.z, bl.w, bh.x, bh.y, bh.z, bh.w};
#pragma unroll
  for (int r = 0; r < 8; ++r) {
    f16x2 c0, c1, c2, c3;
    ld4h(W2m + r * 16, c0, c1, c2, c3);
    float o = fdot2(c0, H2[0], bb[r]);
    o = fdot2(c1, H2[1], o);
    o = fdot2(c2, H2[2], o);
    o = fdot2(c3, H2[3], o);
    out8[r] = o;
    if constexpr (JVP) {
      float jo = fdot2(c0, G2[0], 0.f);
      jo = fdot2(c1, G2[1], jo);
      jo = fdot2(c2, G2[2], jo);
      jo = fdot2(c3, G2[3], jo);
      jout8[r] = jo;
    }
  }
}

}  // namespace

// 256 threads = 32 elements/block, grid 512 -> 2048 waves = 2/SIMD.
// LDS = 42 KiB -> 2+ blocks/CU.
__global__ __launch_bounds__(256, 2) void nf_policy_kernel(
    const float* __restrict__ x, const float* __restrict__ xs,
    const float* __restrict__ gW0, const float* __restrict__ gb0,
    const float* __restrict__ gW1, const float* __restrict__ gb1,
    const float* __restrict__ gW2, const float* __restrict__ gb2,
    float* __restrict__ out) {
  __shared__ __align__(16) f16x2 hW0[4096];  // [32m][8j][16 k-pairs]
  __shared__ __align__(16) f16x2 hW1[1024];  // [32m][8j][4 (p,p+4)-pairs]
  __shared__ __align__(16) f16x2 hW2[4096];  // [32m][8r][4q][4 (p,p+4)-pairs]
  __shared__ __align__(16) float sB0[256];   // [32m][8]
  __shared__ __align__(16) float sB1[256];   // [32m][8]
  __shared__ __align__(16) float sB2[1024];  // [32m][32]

  const int tid = threadIdx.x;
  // ---- stage weights (fp32 global -> f16x2 LDS) ----
  for (int t = tid; t < 4096; t += 256)
    hW0[t] = pk(gW0[2 * t], gW0[2 * t + 1]);
  for (int t = tid; t < 1024; t += 256) {
    const int m = t >> 5, j = (t >> 2) & 7, p = t & 3;
    const float* base = gW1 + m * 64 + j * 8 + p;
    hW1[t] = pk(base[0], base[4]);
  }
  for (int t = tid; t < 4096; t += 256) {
    const int m = t >> 7, r = (t >> 4) & 7, qq = (t >> 2) & 3, p = t & 3;
    const float* base = gW2 + m * 256 + (qq * 8 + r) * 8 + p;
    hW2[t] = pk(base[0], base[4]);
  }
  for (int t = tid; t < 256; t += 256) {
    sB0[t] = gb0[t];
    sB1[t] = gb1[t];
  }
  for (int t = tid; t < 1024; t += 256) sB2[t] = gb2[t];
  __syncthreads();

  const int e = blockIdx.x * 32 + (tid >> 3);
  const int q = tid & 3;
  const bool hb = (tid >> 2) & 1;  // 0: t-net, 1: s-net

  float lo8[8], up8[8], av8[8], bv8[8];
  {
    const float4* xl = (const float4*)(x + (size_t)e * 64 + q * 8);
    const float4* xu = (const float4*)(x + (size_t)e * 64 + 32 + q * 8);
    const float4* sl = (const float4*)(xs + (size_t)e * 64 + q * 8);
    const float4* su = (const float4*)(xs + (size_t)e * 64 + 32 + q * 8);
    float4 a, c;
    a = xl[0]; c = sl[0];
    lo8[0] = a.x; lo8[1] = a.y; lo8[2] = a.z; lo8[3] = a.w;
    av8[0] = -2.f * (a.x - c.x); av8[1] = -2.f * (a.y - c.y);
    av8[2] = -2.f * (a.z - c.z); av8[3] = -2.f * (a.w - c.w);
    a = xl[1]; c = sl[1];
    lo8[4] = a.x; lo8[5] = a.y; lo8[6] = a.z; lo8[7] = a.w;
    av8[4] = -2.f * (a.x - c.x); av8[5] = -2.f * (a.y - c.y);
    av8[6] = -2.f * (a.z - c.z); av8[7] = -2.f * (a.w - c.w);
    a = xu[0]; c = su[0];
    up8[0] = a.x; up8[1] = a.y; up8[2] = a.z; up8[3] = a.w;
    bv8[0] = -2.f * (a.x - c.x); bv8[1] = -2.f * (a.y - c.y);
    bv8[2] = -2.f * (a.z - c.z); bv8[3] = -2.f * (a.w - c.w);
    a = xu[1]; c = su[1];
    up8[4] = a.x; up8[5] = a.y; up8[6] = a.z; up8[7] = a.w;
    bv8[4] = -2.f * (a.x - c.x); bv8[5] = -2.f * (a.y - c.y);
    bv8[6] = -2.f * (a.z - c.z); bv8[7] = -2.f * (a.w - c.w);
  }

  float r8[8], jr8[8], t8[8], s8[8], ut8[8], us8[8];

  // ---------------- forward: z = phi(x) ----------------
#pragma unroll 1
  for (int i = 0; i < NSTEP; ++i) {
    {
      const int m = i * 4 + (int)hb;  // t1 / s1
      net_apply<false>(hW0, hW1, hW2, sB0, sB1, sB2, m, q, lo8, nullptr, r8,
                       nullptr);
#pragma unroll
      for (int k = 0; k < 8; ++k) {
        float o = swz_x4(r8[k]);
        t8[k] = hb ? o : r8[k];
        s8[k] = hb ? r8[k] : o;
      }
#pragma unroll
      for (int k = 0; k < 8; ++k) up8[k] = fmaf(up8[k], __expf(s8[k]), t8[k]);
    }
    {
      const int m = i * 4 + 2 + (int)hb;  // t2 / s2
      net_apply<false>(hW0, hW1, hW2, sB0, sB1, sB2, m, q, up8, nullptr, r8,
                       nullptr);
#pragma unroll
      for (int k = 0; k < 8; ++k) {
        float o = swz_x4(r8[k]);
        t8[k] = hb ? o : r8[k];
        s8[k] = hb ? r8[k] : o;
      }
#pragma unroll
      for (int k = 0; k < 8; ++k) lo8[k] = fmaf(lo8[k], __expf(s8[k]), t8[k]);
    }
  }

  // ------------- backward: y = J^{-1} g, inverting the flow -------------
#pragma unroll 1
  for (int i = NSTEP - 1; i >= 0; --i) {
    {  // T2^{-1}: eval t2/s2 at up', JVP at bv
      const int m = i * 4 + 2 + (int)hb;
      net_apply<true>(hW0, hW1, hW2, sB0, sB1, sB2, m, q, up8, bv8, r8, jr8);
#pragma unroll
      for (int k = 0; k < 8; ++k) {
        float o = swz_x4(r8[k]);
        t8[k] = hb ? o : r8[k];
        s8[k] = hb ? r8[k] : o;
        float ou = swz_x4(jr8[k]);
        ut8[k] = hb ? ou : jr8[k];
        us8[k] = hb ? jr8[k] : ou;
      }
#pragma unroll
      for (int k = 0; k < 8; ++k) {
        const float es = __expf(s8[k]);
        const float esi = __expf(-s8[k]);
        lo8[k] = (lo8[k] - t8[k]) * esi;  // pre-step lo
        av8[k] = (av8[k] - ut8[k] - lo8[k] * es * us8[k]) * esi;
      }
    }
    {  // T1^{-1}: eval t1/s1 at lo (pre-step), JVP at av (updated)
      const int m = i * 4 + (int)hb;
      net_apply<true>(hW0, hW1, hW2, sB0, sB1, sB2, m, q, lo8, av8, r8, jr8);
#pragma unroll
      for (int k = 0; k < 8; ++k) {
        float o = swz_x4(r8[k]);
        t8[k] = hb ? o : r8[k];
        s8[k] = hb ? r8[k] : o;
        float ou = swz_x4(jr8[k]);
        ut8[k] = hb ? ou : jr8[k];
        us8[k] = hb ? jr8[k] : ou;
      }
#pragma unroll
      for (int k = 0; k < 8; ++k) {
        const float es = __expf(s8[k]);
        const float esi = __expf(-s8[k]);
        up8[k] = (up8[k] - t8[k]) * esi;  // pre-step up
        bv8[k] = (bv8[k] - ut8[k] - up8[k] * es * us8[k]) * esi;
      }
    }
  }

  if (!hb) {
    float4* ol = (float4*)(out + (size_t)e * 64 + q * 8);
    float4* ou = (float4*)(out + (size_t)e * 64 + 32 + q * 8);
    float4 v;
    v.x = av8[0]; v.y = av8[1]; v.z = av8[2]; v.w = av8[3]; ol[0] = v;
    v.x = av8[4]; v.y = av8[5]; v.z = av8[6]; v.w = av8[7]; ol[1] = v;
    v.x = bv8[0]; v.y = bv8[1]; v.z = bv8[2]; v.w = bv8[3]; ou[0] = v;
    v.x = bv8[4]; v.y = bv8[5]; v.z = bv8[6]; v.w = bv8[7]; ou[1] = v;
  }
}

extern "C" void kernel_launch(void* const* d_in, const int* in_sizes, int n_in,
                              void* d_out, int out_size, void* d_ws,
                              size_t ws_size, hipStream_t stream) {
  const float* x  = (const float*)d_in[0];
  const float* xs = (const float*)d_in[1];
  const float* W0 = (const float*)d_in[2];
  const float* b0 = (const float*)d_in[3];
  const float* W1 = (const float*)d_in[4];
  const float* b1 = (const float*)d_in[5];
  const float* W2 = (const float*)d_in[6];
  const float* b2 = (const float*)d_in[7];
  float* out = (float*)d_out;

  dim3 grid(NB * 8 / 256);  // 512 blocks, 32 elements each
  dim3 block(256);
  nf_policy_kernel<<<grid, block, 0, stream>>>(x, xs, W0, b0, W1, b1, W2, b2,
                                               out);
}